// Round 5
// baseline (242.376 us; speedup 1.0000x reference)
//
#include <hip/hip_runtime.h>

#define NPTS 131072
#define DIM  128
#define KC   1024

using half8  = __attribute__((ext_vector_type(8))) _Float16;
using f32x16 = __attribute__((ext_vector_type(16))) float;

static __device__ __forceinline__ unsigned umin_(unsigned a, unsigned b){ return a < b ? a : b; }
static __device__ __forceinline__ unsigned umax_(unsigned a, unsigned b){ return a > b ? a : b; }

// ws layout (bytes):
//   [0, 262144)        f16 eh codebook image, 16 chunks x 16KB, pre-swizzled
//   [262144, 266240)   eeW[1024] = 0.5*||e||^2 - 512   (uniform shift, argmax-safe)
//   [266240, 790528)   best[131072] packed top-3 (10 bits each)
//   [790528, 792576)   bsum[512]

// ---------------- prep: 0.5*||e||^2 - 512 ----------------
__global__ void vq_ee(const float* __restrict__ emb, float* __restrict__ eeW) {
    int gid  = blockIdx.x * blockDim.x + threadIdx.x;
    int w    = gid >> 6;          // code id (1024 waves)
    int lane = threadIdx.x & 63;
    const float* e = emb + (size_t)w * DIM;
    float a = e[lane];
    float b = e[lane + 64];
    float v = a * a + b * b;
    #pragma unroll
    for (int o = 32; o > 0; o >>= 1) v += __shfl_down(v, o);
    if (lane == 0) eeW[w] = 0.5f * v - 512.0f;
}

// ---------------- prep: f16 codebook image, pre-swizzled for linear LDS copy
// chunk (64 codes): row r (code&63) at byte r*256; element k at byte (2k)^((r&7)<<4)
__global__ void vq_prep(const float* __restrict__ emb, unsigned short* __restrict__ wsE) {
    int t = blockIdx.x * 256 + threadIdx.x;      // 0..131071
    int code = t >> 7, k = t & 127;
    float v = emb[t];
    _Float16 h = (_Float16)v;
    unsigned short hu = __builtin_bit_cast(unsigned short, h);
    int chunk = code >> 6, r = code & 63;
    int o = (r << 8) + ((k << 1) ^ ((r & 7) << 4));
    wsE[((size_t)chunk * 16384 + (size_t)o) >> 1] = hu;
}

// ---------------- pass A: 32x32x16 f16 MFMA + packed-key top-3 ----------------
__global__ __launch_bounds__(256, 3) void vq_mfma(const float* __restrict__ x,
                                                  const unsigned short* __restrict__ wsE,
                                                  const float* __restrict__ eeW,
                                                  int* __restrict__ best) {
    __shared__ __attribute__((aligned(128))) char lds[16384];
    const int tid  = threadIdx.x;
    const int lane = tid & 63, wv = tid >> 6;
    const int col  = lane & 31;        // A row / B col / C col
    const int h    = lane >> 5;        // k-slot half
    const int rowbase = blockIdx.x * 128 + wv * 32;

    // A fragments: x row (rowbase+col), k = kc*16 + h*8 + j.  xh = fp16(x), xl = x - xh.
    half8 ah[8], al[8];
    {
        const float* xr = x + (size_t)(rowbase + col) * DIM;
        #pragma unroll
        for (int kc = 0; kc < 8; ++kc) {
            const float4* p = reinterpret_cast<const float4*>(xr + kc * 16 + h * 8);
            float4 v0 = p[0], v1 = p[1];
            float vv[8] = {v0.x, v0.y, v0.z, v0.w, v1.x, v1.y, v1.z, v1.w};
            half8 hh, ll;
            #pragma unroll
            for (int j = 0; j < 8; ++j) {
                _Float16 hv = (_Float16)vv[j];
                float res = vv[j] - (float)hv;
                hh[j] = hv;
                ll[j] = (_Float16)res;
            }
            ah[kc] = hh; al[kc] = ll;
        }
    }

    // top-3 packed keys per owned C-row (16 rows/lane)
    unsigned m1[16], m2[16], m3[16];
    #pragma unroll
    for (int i = 0; i < 16; ++i) { m1[i] = 0u; m2[i] = 0u; m3[i] = 0u; }

    for (int ch = 0; ch < 16; ++ch) {
        __syncthreads();   // previous chunk's reads complete
        {
            const char* src = (const char*)wsE + (size_t)ch * 16384 + (size_t)wv * 4096;
            #pragma unroll
            for (int it = 0; it < 4; ++it) {
                __builtin_amdgcn_global_load_lds(
                    (const __attribute__((address_space(1))) void*)(src + it * 1024 + lane * 16),
                    (__attribute__((address_space(3))) void*)(lds + wv * 4096 + it * 1024),
                    16, 0, 0);
            }
        }
        __syncthreads();   // vmcnt drained before barrier

        #pragma unroll
        for (int ct = 0; ct < 2; ++ct) {
            const int r    = ct * 32 + col;            // B row within chunk
            const int code = ch * 64 + r;
            const float    eec   = eeW[code];          // issued early, consumed after MFMAs
            const unsigned codeC = (unsigned)(1023 - code);
            const int swz = (r & 7) << 4;
            f32x16 acch = {}, accl = {};               // two chains: hh and lh
            #pragma unroll
            for (int kc = 0; kc < 8; ++kc) {
                int bo = (r << 8) + ((kc * 32 + h * 16) ^ swz);
                half8 bh = *reinterpret_cast<const half8*>(lds + bo);
                acch = __builtin_amdgcn_mfma_f32_32x32x16_f16(ah[kc], bh, acch, 0, 0, 0);
                accl = __builtin_amdgcn_mfma_f32_32x32x16_f16(al[kc], bh, accl, 0, 0, 0);
            }
            #pragma unroll
            for (int i = 0; i < 16; ++i) {
                float sp = (acch[i] + accl[i]) - eec;   // = x.eh - 0.5||e||^2 + 512 > 0
                unsigned u   = __builtin_bit_cast(unsigned, sp);
                unsigned key = (u & 0xFFFFFC00u) | (codeC & 1023u);   // v_bfi
                unsigned t1 = umin_(m1[i], key);
                m1[i] = umax_(m1[i], key);
                unsigned t2 = umin_(m2[i], t1);
                m2[i] = umax_(m2[i], t1);
                m3[i] = umax_(m3[i], t2);
            }
        }
    }

    // merge top-3 across the 32 lanes sharing h (xor masks stay within the half)
    #pragma unroll
    for (int i = 0; i < 16; ++i) {
        unsigned a1 = m1[i], a2 = m2[i], a3 = m3[i];
        #pragma unroll
        for (int mk = 1; mk < 32; mk <<= 1) {
            unsigned b1 = (unsigned)__shfl_xor((int)a1, mk, 64);
            unsigned b2 = (unsigned)__shfl_xor((int)a2, mk, 64);
            unsigned b3 = (unsigned)__shfl_xor((int)a3, mk, 64);
            unsigned c1 = umax_(a1, b1), t1 = umin_(a1, b1);
            unsigned u1 = umax_(a2, b2), u2 = umin_(a2, b2);
            unsigned c2 = umax_(t1, u1), t2 = umin_(t1, u1);
            unsigned c3 = umax_(umax_(t2, u2), umax_(a3, b3));
            a1 = c1; a2 = c2; a3 = c3;
        }
        if (col == 0) {
            int row = rowbase + ((i & 3) + 8 * (i >> 2) + 4 * h);
            int i1 = 1023 - (int)(a1 & 1023u);
            int i2 = 1023 - (int)(a2 & 1023u);
            int i3 = 1023 - (int)(a3 & 1023u);
            best[row] = i1 | (i2 << 10) | (i3 << 20);
        }
    }
}

// ---------------- pass B: exact fp32 over 3 candidates, gather, loss -------
__global__ __launch_bounds__(256) void vq_fin(const float* __restrict__ x,
                                              const float* __restrict__ emb,
                                              const int* __restrict__ best,
                                              float* __restrict__ out,
                                              float* __restrict__ bsum) {
    const int p = blockIdx.x * 256 + threadIdx.x;

    float4 xr[32];
    const float4* xv = reinterpret_cast<const float4*>(x + (size_t)p * DIM);
    #pragma unroll
    for (int i = 0; i < 32; ++i) xr[i] = xv[i];

    int pk = best[p];
    int ia = pk & 1023, ib = (pk >> 10) & 1023, ic = (pk >> 20) & 1023;

    const float4* ea = reinterpret_cast<const float4*>(emb + (size_t)ia * DIM);
    const float4* eb = reinterpret_cast<const float4*>(emb + (size_t)ib * DIM);
    const float4* ec = reinterpret_cast<const float4*>(emb + (size_t)ic * DIM);
    float da = 0.f, db = 0.f, dc = 0.f;
    #pragma unroll
    for (int i = 0; i < 32; ++i) {
        float4 va = ea[i], vb = eb[i], vc = ec[i], xx = xr[i];
        float ax = va.x - xx.x, ay = va.y - xx.y, az = va.z - xx.z, aw = va.w - xx.w;
        float bx = vb.x - xx.x, by = vb.y - xx.y, bz = vb.z - xx.z, bw = vb.w - xx.w;
        float cx = vc.x - xx.x, cy = vc.y - xx.y, cz = vc.z - xx.z, cw = vc.w - xx.w;
        da += ax * ax + ay * ay + az * az + aw * aw;
        db += bx * bx + by * by + bz * bz + bw * bw;
        dc += cx * cx + cy * cy + cz * cz + cw * cw;
    }
    int idx = ia; float dm = da;
    if (db < dm || (db == dm && ib < idx)) { dm = db; idx = ib; }
    if (dc < dm || (dc == dm && ic < idx)) { dm = dc; idx = ic; }

    out[p] = (float)idx;

    const float4* q4 = reinterpret_cast<const float4*>(emb + (size_t)idx * DIM);
    float4* oq = reinterpret_cast<float4*>(out + (size_t)NPTS + (size_t)p * DIM);
    float lsum = 0.f;
    #pragma unroll
    for (int i = 0; i < 32; ++i) {
        float4 qv = q4[i];
        oq[i] = qv;
        float dx = qv.x - xr[i].x;
        float dy = qv.y - xr[i].y;
        float dz = qv.z - xr[i].z;
        float dw = qv.w - xr[i].w;
        lsum += dx * dx + dy * dy + dz * dz + dw * dw;
    }
    __shared__ float red[4];
    #pragma unroll
    for (int o = 32; o > 0; o >>= 1) lsum += __shfl_down(lsum, o);
    int lane = threadIdx.x & 63, wvl = threadIdx.x >> 6;
    if (lane == 0) red[wvl] = lsum;
    __syncthreads();
    if (threadIdx.x == 0) bsum[blockIdx.x] = (red[0] + red[1]) + (red[2] + red[3]);
}

__global__ void vq_finalize(const float* __restrict__ bsum, float* __restrict__ out) {
    __shared__ float red[8];
    int t = threadIdx.x;  // 512 threads
    float v = bsum[t];
    #pragma unroll
    for (int o = 32; o > 0; o >>= 1) v += __shfl_down(v, o);
    if ((t & 63) == 0) red[t >> 6] = v;
    __syncthreads();
    if (t == 0) {
        float s = 0.f;
        #pragma unroll
        for (int i = 0; i < 8; ++i) s += red[i];
        out[(size_t)NPTS + (size_t)NPTS * DIM] = 1.25f * s / 16777216.0f;
    }
}

// ---------------- fallback (round-2 proven path; eeW shift is argmax-safe) ----
__global__ __launch_bounds__(256, 1) void vq_main(const float* __restrict__ x,
                                                  const float* __restrict__ emb,
                                                  const float* __restrict__ eeW,
                                                  float* __restrict__ out,
                                                  float* __restrict__ bsum) {
    const int p = blockIdx.x * 256 + threadIdx.x;
    float4 xr[32];
    const float4* xv = reinterpret_cast<const float4*>(x + (size_t)p * DIM);
    #pragma unroll
    for (int i = 0; i < 32; ++i) xr[i] = xv[i];
    float bestv = -3.4e38f; int bi = 0;
    for (int k = 0; k < KC; ++k) {
        const int ku = __builtin_amdgcn_readfirstlane(k);
        const float4* e4 = reinterpret_cast<const float4*>(emb + (size_t)ku * DIM);
        float a0 = 0.f, a1 = 0.f, a2 = 0.f, a3 = 0.f;
        #pragma unroll
        for (int i = 0; i < 32; ++i) {
            float4 ev = e4[i];
            a0 = fmaf(xr[i].x, ev.x, a0);
            a1 = fmaf(xr[i].y, ev.y, a1);
            a2 = fmaf(xr[i].z, ev.z, a2);
            a3 = fmaf(xr[i].w, ev.w, a3);
        }
        float s = ((a0 + a1) + (a2 + a3)) - eeW[ku];
        if (s > bestv) { bestv = s; bi = k; }
    }
    out[p] = (float)bi;
    const float4* q4 = reinterpret_cast<const float4*>(emb + (size_t)bi * DIM);
    float4* oq = reinterpret_cast<float4*>(out + (size_t)NPTS + (size_t)p * DIM);
    float lsum = 0.f;
    #pragma unroll
    for (int i = 0; i < 32; ++i) {
        float4 qv = q4[i];
        oq[i] = qv;
        float dx = qv.x - xr[i].x;
        float dy = qv.y - xr[i].y;
        float dz = qv.z - xr[i].z;
        float dw = qv.w - xr[i].w;
        lsum += dx * dx + dy * dy + dz * dz + dw * dw;
    }
    __shared__ float red[4];
    #pragma unroll
    for (int o = 32; o > 0; o >>= 1) lsum += __shfl_down(lsum, o);
    int lane = threadIdx.x & 63, wvl = threadIdx.x >> 6;
    if (lane == 0) red[wvl] = lsum;
    __syncthreads();
    if (threadIdx.x == 0) bsum[blockIdx.x] = (red[0] + red[1]) + (red[2] + red[3]);
}

extern "C" void kernel_launch(void* const* d_in, const int* in_sizes, int n_in,
                              void* d_out, int out_size, void* d_ws, size_t ws_size,
                              hipStream_t stream) {
    const float* x   = (const float*)d_in[0];
    const float* emb = (const float*)d_in[1];
    float* out = (float*)d_out;
    char*  ws  = (char*)d_ws;

    if (ws_size >= 792576) {
        unsigned short* wsE = (unsigned short*)ws;           // 256 KB f16 image
        float* eeW  = (float*)(ws + 262144);                 // 4 KB
        int*   best = (int*)(ws + 266240);                   // 512 KB
        float* bsum = (float*)(ws + 790528);                 // 2 KB
        vq_prep<<<512, 256, 0, stream>>>(emb, wsE);
        vq_ee<<<256, 256, 0, stream>>>(emb, eeW);
        vq_mfma<<<1024, 256, 0, stream>>>(x, wsE, eeW, best);
        vq_fin<<<512, 256, 0, stream>>>(x, emb, best, out, bsum);
        vq_finalize<<<1, 512, 0, stream>>>(bsum, out);
    } else {
        float* eeW  = (float*)ws;
        float* bsum = (float*)ws + 1024;
        vq_ee<<<256, 256, 0, stream>>>(emb, eeW);
        vq_main<<<512, 256, 0, stream>>>(x, emb, eeW, out, bsum);
        vq_finalize<<<1, 512, 0, stream>>>(bsum, out);
    }
}

// Round 6
// 137.166 us; speedup vs baseline: 1.7670x; 1.7670x over previous
//
#include <hip/hip_runtime.h>

#define NPTS 131072
#define DIM  128
#define KC   1024

using half8 = __attribute__((ext_vector_type(8))) _Float16;
using f32x4 = __attribute__((ext_vector_type(4))) float;

static __device__ __forceinline__ unsigned umin_(unsigned a, unsigned b){ return a < b ? a : b; }
static __device__ __forceinline__ unsigned umax_(unsigned a, unsigned b){ return a > b ? a : b; }

// ws layout (bytes):
//   [0, 262144)        f16 codebook image, 16 chunks x 16KB, pre-swizzled
//   [262144, 266240)   eeW[1024] = 0.5*||e||^2 - 512
//   [266240, 790528)   best[131072] packed top-3 (10 bits each)
//   [790528, 792576)   bsum[512]

// ---- prep: f16 swizzled image + eeW, one wave per code ----
__global__ void vq_prep(const float* __restrict__ emb, unsigned short* __restrict__ wsE,
                        float* __restrict__ eeW) {
    int lane = threadIdx.x & 63, wv = threadIdx.x >> 6;
    int code = blockIdx.x * 4 + wv;                 // 256 blocks x 4 waves = 1024 codes
    const float* e = emb + (size_t)code * DIM;
    float a = e[lane], b = e[lane + 64];

    int chunk = code >> 6, r = code & 63, swz = (r & 7) << 4;
    size_t base = (size_t)chunk * 16384 + (size_t)(r << 8);
    _Float16 ha = (_Float16)a, hb = (_Float16)b;
    wsE[(base + (size_t)(((lane << 1))        ^ swz)) >> 1] = __builtin_bit_cast(unsigned short, ha);
    wsE[(base + (size_t)(((lane + 64) << 1)   ^ swz)) >> 1] = __builtin_bit_cast(unsigned short, hb);

    float v = a * a + b * b;
    #pragma unroll
    for (int o = 32; o > 0; o >>= 1) v += __shfl_down(v, o);
    if (lane == 0) eeW[code] = 0.5f * v - 512.0f;
}

// ---- pass A: 16x16x32 f16 MFMA (single-term) + packed-key top-3, dbuf LDS ----
__global__ __launch_bounds__(256, 4) void vq_mfma(const float* __restrict__ x,
                                                  const unsigned short* __restrict__ wsE,
                                                  const float* __restrict__ eeW,
                                                  int* __restrict__ best) {
    __shared__ __attribute__((aligned(128))) char lds[2][16384];
    const int tid  = threadIdx.x;
    const int lane = tid & 63, wv = tid >> 6;
    const int g    = lane >> 4, c = lane & 15;
    const int blockbase = blockIdx.x * 128;

    // A fragments: x row (blockbase + wv*32 + rt*16 + c), k = kc*32 + g*8 + j
    half8 ah[2][4];
    #pragma unroll
    for (int rt = 0; rt < 2; ++rt) {
        const float* xr = x + (size_t)(blockbase + wv * 32 + rt * 16 + c) * DIM;
        #pragma unroll
        for (int kc = 0; kc < 4; ++kc) {
            const float4* p = reinterpret_cast<const float4*>(xr + kc * 32 + g * 8);
            float4 v0 = p[0], v1 = p[1];
            half8 hh;
            hh[0] = (_Float16)v0.x; hh[1] = (_Float16)v0.y;
            hh[2] = (_Float16)v0.z; hh[3] = (_Float16)v0.w;
            hh[4] = (_Float16)v1.x; hh[5] = (_Float16)v1.y;
            hh[6] = (_Float16)v1.z; hh[7] = (_Float16)v1.w;
            ah[rt][kc] = hh;
        }
    }

    unsigned m1[8], m2[8], m3[8];          // [rt*4+q], packed keys, descending
    #pragma unroll
    for (int i = 0; i < 8; ++i) { m1[i] = 0u; m2[i] = 0u; m3[i] = 0u; }

    #define STAGE(BUF, CH)                                                                   \
        do {                                                                                 \
            const char* src_ = (const char*)wsE + (size_t)(CH) * 16384 + (size_t)wv * 4096;  \
            char* dst_ = &lds[(BUF)][0] + wv * 4096;                                         \
            _Pragma("unroll")                                                                \
            for (int it = 0; it < 4; ++it) {                                                 \
                __builtin_amdgcn_global_load_lds(                                            \
                    (const __attribute__((address_space(1))) void*)(src_ + it * 1024 + lane * 16), \
                    (__attribute__((address_space(3))) void*)(dst_ + it * 1024),             \
                    16, 0, 0);                                                               \
            }                                                                                \
        } while (0)

    STAGE(0, 0);
    __syncthreads();                       // chunk 0 staged (vmcnt drained by barrier)

    for (int ch = 0; ch < 16; ++ch) {
        if (ch < 15) STAGE((ch + 1) & 1, ch + 1);   // prefetch next chunk (other buffer)
        const char* L = &lds[ch & 1][0];

        #pragma unroll
        for (int ct = 0; ct < 4; ++ct) {
            const int r    = ct * 16 + c;            // code row within chunk (= C col)
            const int swz  = (r & 7) << 4;
            const int code = ch * 64 + r;
            const float    eec   = eeW[code];
            const unsigned codeC = (unsigned)(1023 - code);
            f32x4 acc0 = {0.f, 0.f, 0.f, 0.f};
            f32x4 acc1 = {0.f, 0.f, 0.f, 0.f};
            #pragma unroll
            for (int kc = 0; kc < 4; ++kc) {
                int bo = (r << 8) + (((kc << 6) + (g << 4)) ^ swz);
                half8 bh = *reinterpret_cast<const half8*>(L + bo);
                acc0 = __builtin_amdgcn_mfma_f32_16x16x32_f16(ah[0][kc], bh, acc0, 0, 0, 0);
                acc1 = __builtin_amdgcn_mfma_f32_16x16x32_f16(ah[1][kc], bh, acc1, 0, 0, 0);
            }
            #pragma unroll
            for (int q = 0; q < 4; ++q) {
                #pragma unroll
                for (int rt = 0; rt < 2; ++rt) {
                    float sp = (rt ? acc1[q] : acc0[q]) - eec;   // > 0 (bias +512)
                    unsigned u   = __builtin_bit_cast(unsigned, sp);
                    unsigned key = (u & 0xFFFFFC00u) | codeC;    // v_and_or
                    const int i = rt * 4 + q;
                    unsigned t1 = umin_(m1[i], key);
                    m1[i] = umax_(m1[i], key);
                    unsigned t2 = umin_(m2[i], t1);
                    m2[i] = umax_(m2[i], t1);
                    m3[i] = umax_(m3[i], t2);
                }
            }
        }
        __syncthreads();   // prefetched loads drained; buffers safe to swap
    }

    // merge top-3 across the 16 code-lanes of each g-group
    #pragma unroll
    for (int rt = 0; rt < 2; ++rt) {
        #pragma unroll
        for (int q = 0; q < 4; ++q) {
            const int i = rt * 4 + q;
            unsigned a1 = m1[i], a2 = m2[i], a3 = m3[i];
            #pragma unroll
            for (int mk = 1; mk < 16; mk <<= 1) {
                unsigned b1 = (unsigned)__shfl_xor((int)a1, mk, 64);
                unsigned b2 = (unsigned)__shfl_xor((int)a2, mk, 64);
                unsigned b3 = (unsigned)__shfl_xor((int)a3, mk, 64);
                unsigned c1 = umax_(a1, b1), t1 = umin_(a1, b1);
                unsigned u1 = umax_(a2, b2), u2 = umin_(a2, b2);
                unsigned c2 = umax_(t1, u1), t2 = umin_(t1, u1);
                unsigned c3 = umax_(umax_(t2, u2), umax_(a3, b3));
                a1 = c1; a2 = c2; a3 = c3;
            }
            if (c == 0) {
                int row = blockbase + wv * 32 + rt * 16 + g * 4 + q;
                int i1 = 1023 - (int)(a1 & 1023u);
                int i2 = 1023 - (int)(a2 & 1023u);
                int i3 = 1023 - (int)(a3 & 1023u);
                best[row] = i1 | (i2 << 10) | (i3 << 20);
            }
        }
    }
    #undef STAGE
}

// ---- pass B: exact fp32 over 3 candidates, gather, loss ----
__global__ __launch_bounds__(256) void vq_fin(const float* __restrict__ x,
                                              const float* __restrict__ emb,
                                              const int* __restrict__ best,
                                              float* __restrict__ out,
                                              float* __restrict__ bsum) {
    const int p = blockIdx.x * 256 + threadIdx.x;

    float4 xr[32];
    const float4* xv = reinterpret_cast<const float4*>(x + (size_t)p * DIM);
    #pragma unroll
    for (int i = 0; i < 32; ++i) xr[i] = xv[i];

    int pk = best[p];
    int ia = pk & 1023, ib = (pk >> 10) & 1023, ic = (pk >> 20) & 1023;

    const float4* ea = reinterpret_cast<const float4*>(emb + (size_t)ia * DIM);
    const float4* eb = reinterpret_cast<const float4*>(emb + (size_t)ib * DIM);
    const float4* ec = reinterpret_cast<const float4*>(emb + (size_t)ic * DIM);
    float da = 0.f, db = 0.f, dc = 0.f;
    #pragma unroll
    for (int i = 0; i < 32; ++i) {
        float4 va = ea[i], vb = eb[i], vc = ec[i], xx = xr[i];
        float ax = va.x - xx.x, ay = va.y - xx.y, az = va.z - xx.z, aw = va.w - xx.w;
        float bx = vb.x - xx.x, by = vb.y - xx.y, bz = vb.z - xx.z, bw = vb.w - xx.w;
        float cx = vc.x - xx.x, cy = vc.y - xx.y, cz = vc.z - xx.z, cw = vc.w - xx.w;
        da += ax * ax + ay * ay + az * az + aw * aw;
        db += bx * bx + by * by + bz * bz + bw * bw;
        dc += cx * cx + cy * cy + cz * cz + cw * cw;
    }
    int idx = ia; float dm = da;
    if (db < dm || (db == dm && ib < idx)) { dm = db; idx = ib; }
    if (dc < dm || (dc == dm && ic < idx)) { dm = dc; idx = ic; }

    out[p] = (float)idx;

    const float4* q4 = reinterpret_cast<const float4*>(emb + (size_t)idx * DIM);
    float4* oq = reinterpret_cast<float4*>(out + (size_t)NPTS + (size_t)p * DIM);
    float lsum = 0.f;
    #pragma unroll
    for (int i = 0; i < 32; ++i) {
        float4 qv = q4[i];
        oq[i] = qv;
        float dx = qv.x - xr[i].x;
        float dy = qv.y - xr[i].y;
        float dz = qv.z - xr[i].z;
        float dw = qv.w - xr[i].w;
        lsum += dx * dx + dy * dy + dz * dz + dw * dw;
    }
    __shared__ float red[4];
    #pragma unroll
    for (int o = 32; o > 0; o >>= 1) lsum += __shfl_down(lsum, o);
    int lane = threadIdx.x & 63, wvl = threadIdx.x >> 6;
    if (lane == 0) red[wvl] = lsum;
    __syncthreads();
    if (threadIdx.x == 0) bsum[blockIdx.x] = (red[0] + red[1]) + (red[2] + red[3]);
}

__global__ void vq_finalize(const float* __restrict__ bsum, float* __restrict__ out) {
    __shared__ float red[8];
    int t = threadIdx.x;  // 512 threads
    float v = bsum[t];
    #pragma unroll
    for (int o = 32; o > 0; o >>= 1) v += __shfl_down(v, o);
    if ((t & 63) == 0) red[t >> 6] = v;
    __syncthreads();
    if (t == 0) {
        float s = 0.f;
        #pragma unroll
        for (int i = 0; i < 8; ++i) s += red[i];
        out[(size_t)NPTS + (size_t)NPTS * DIM] = 1.25f * s / 16777216.0f;
    }
}

// ---- fallback (round-2 proven path; eeW bias is argmax-safe) ----
__global__ void vq_ee(const float* __restrict__ emb, float* __restrict__ eeW) {
    int gid  = blockIdx.x * blockDim.x + threadIdx.x;
    int w    = gid >> 6;
    int lane = threadIdx.x & 63;
    const float* e = emb + (size_t)w * DIM;
    float a = e[lane];
    float b = e[lane + 64];
    float v = a * a + b * b;
    #pragma unroll
    for (int o = 32; o > 0; o >>= 1) v += __shfl_down(v, o);
    if (lane == 0) eeW[w] = 0.5f * v - 512.0f;
}

__global__ __launch_bounds__(256, 1) void vq_main(const float* __restrict__ x,
                                                  const float* __restrict__ emb,
                                                  const float* __restrict__ eeW,
                                                  float* __restrict__ out,
                                                  float* __restrict__ bsum) {
    const int p = blockIdx.x * 256 + threadIdx.x;
    float4 xr[32];
    const float4* xv = reinterpret_cast<const float4*>(x + (size_t)p * DIM);
    #pragma unroll
    for (int i = 0; i < 32; ++i) xr[i] = xv[i];
    float bestv = -3.4e38f; int bi = 0;
    for (int k = 0; k < KC; ++k) {
        const int ku = __builtin_amdgcn_readfirstlane(k);
        const float4* e4 = reinterpret_cast<const float4*>(emb + (size_t)ku * DIM);
        float a0 = 0.f, a1 = 0.f, a2 = 0.f, a3 = 0.f;
        #pragma unroll
        for (int i = 0; i < 32; ++i) {
            float4 ev = e4[i];
            a0 = fmaf(xr[i].x, ev.x, a0);
            a1 = fmaf(xr[i].y, ev.y, a1);
            a2 = fmaf(xr[i].z, ev.z, a2);
            a3 = fmaf(xr[i].w, ev.w, a3);
        }
        float s = ((a0 + a1) + (a2 + a3)) - eeW[ku];
        if (s > bestv) { bestv = s; bi = k; }
    }
    out[p] = (float)bi;
    const float4* q4 = reinterpret_cast<const float4*>(emb + (size_t)bi * DIM);
    float4* oq = reinterpret_cast<float4*>(out + (size_t)NPTS + (size_t)p * DIM);
    float lsum = 0.f;
    #pragma unroll
    for (int i = 0; i < 32; ++i) {
        float4 qv = q4[i];
        oq[i] = qv;
        float dx = qv.x - xr[i].x;
        float dy = qv.y - xr[i].y;
        float dz = qv.z - xr[i].z;
        float dw = qv.w - xr[i].w;
        lsum += dx * dx + dy * dy + dz * dz + dw * dw;
    }
    __shared__ float red[4];
    #pragma unroll
    for (int o = 32; o > 0; o >>= 1) lsum += __shfl_down(lsum, o);
    int lane = threadIdx.x & 63, wvl = threadIdx.x >> 6;
    if (lane == 0) red[wvl] = lsum;
    __syncthreads();
    if (threadIdx.x == 0) bsum[blockIdx.x] = (red[0] + red[1]) + (red[2] + red[3]);
}

extern "C" void kernel_launch(void* const* d_in, const int* in_sizes, int n_in,
                              void* d_out, int out_size, void* d_ws, size_t ws_size,
                              hipStream_t stream) {
    const float* x   = (const float*)d_in[0];
    const float* emb = (const float*)d_in[1];
    float* out = (float*)d_out;
    char*  ws  = (char*)d_ws;

    if (ws_size >= 792576) {
        unsigned short* wsE = (unsigned short*)ws;           // 256 KB f16 image
        float* eeW  = (float*)(ws + 262144);                 // 4 KB
        int*   best = (int*)(ws + 266240);                   // 512 KB
        float* bsum = (float*)(ws + 790528);                 // 2 KB
        vq_prep<<<256, 256, 0, stream>>>(emb, wsE, eeW);
        vq_mfma<<<1024, 256, 0, stream>>>(x, wsE, eeW, best);
        vq_fin<<<512, 256, 0, stream>>>(x, emb, best, out, bsum);
        vq_finalize<<<1, 512, 0, stream>>>(bsum, out);
    } else {
        float* eeW  = (float*)ws;
        float* bsum = (float*)ws + 1024;
        vq_ee<<<256, 256, 0, stream>>>(emb, eeW);
        vq_main<<<512, 256, 0, stream>>>(x, emb, eeW, out, bsum);
        vq_finalize<<<1, 512, 0, stream>>>(bsum, out);
    }
}

// Round 7
// 117.767 us; speedup vs baseline: 2.0581x; 1.1647x over previous
//
#include <hip/hip_runtime.h>

#define NPTS 131072
#define DIM  128
#define KC   1024
#define CHB  16640   // LDS chunk buffer: 16KB swizzled f16 codes + 256B eeW

using half8 = __attribute__((ext_vector_type(8))) _Float16;
using f32x4 = __attribute__((ext_vector_type(4))) float;

static __device__ __forceinline__ unsigned umax_(unsigned a, unsigned b){ return a > b ? a : b; }
static __device__ __forceinline__ unsigned med3u(unsigned a, unsigned b, unsigned c){
    unsigned d;
    asm("v_med3_u32 %0, %1, %2, %3" : "=v"(d) : "v"(a), "v"(b), "v"(c));
    return d;
}

// ws layout (bytes):
//   [0, 262144)        f16 codebook image, 16 chunks x 16KB, pre-swizzled
//   [262144, 266240)   eeW[1024] = 0.5*||e||^2 - 512   (chunk-contiguous)
//   [266240, 270336)   bsum[1024]

// ---- prep: f16 swizzled image + eeW, one wave per code ----
__global__ void vq_prep(const float* __restrict__ emb, unsigned short* __restrict__ wsE,
                        float* __restrict__ eeW) {
    int lane = threadIdx.x & 63, wv = threadIdx.x >> 6;
    int code = blockIdx.x * 4 + wv;                 // 256 blocks x 4 waves = 1024 codes
    const float* e = emb + (size_t)code * DIM;
    float a = e[lane], b = e[lane + 64];

    int chunk = code >> 6, r = code & 63, swz = (r & 7) << 4;
    size_t base = (size_t)chunk * 16384 + (size_t)(r << 8);
    _Float16 ha = (_Float16)a, hb = (_Float16)b;
    wsE[(base + (size_t)(((lane << 1))        ^ swz)) >> 1] = __builtin_bit_cast(unsigned short, ha);
    wsE[(base + (size_t)(((lane + 64) << 1)   ^ swz)) >> 1] = __builtin_bit_cast(unsigned short, hb);

    float v = a * a + b * b;
    #pragma unroll
    for (int o = 32; o > 0; o >>= 1) v += __shfl_down(v, o);
    if (lane == 0) eeW[code] = 0.5f * v - 512.0f;
}

// ---- fused pass: 16x16x32 f16 MFMA + med3 top-3 + exact-fp32 epilogue ----
__global__ __launch_bounds__(256, 4) void vq_mfma(const float* __restrict__ x,
                                                  const float* __restrict__ emb,
                                                  const unsigned short* __restrict__ wsE,
                                                  const float* __restrict__ eeW,
                                                  float* __restrict__ out,
                                                  float* __restrict__ bsum) {
    __shared__ __attribute__((aligned(128))) char lds[2][CHB];
    const int tid  = threadIdx.x;
    const int lane = tid & 63, wv = tid >> 6;
    const int g    = lane >> 4, c = lane & 15;
    const int blockbase = blockIdx.x * 128;

    // A fragments: x row (blockbase + wv*32 + rt*16 + c), k = kc*32 + g*8 + j
    half8 ah[2][4];
    #pragma unroll
    for (int rt = 0; rt < 2; ++rt) {
        const float* xr = x + (size_t)(blockbase + wv * 32 + rt * 16 + c) * DIM;
        #pragma unroll
        for (int kc = 0; kc < 4; ++kc) {
            const float4* p = reinterpret_cast<const float4*>(xr + kc * 32 + g * 8);
            float4 v0 = p[0], v1 = p[1];
            half8 hh;
            hh[0] = (_Float16)v0.x; hh[1] = (_Float16)v0.y;
            hh[2] = (_Float16)v0.z; hh[3] = (_Float16)v0.w;
            hh[4] = (_Float16)v1.x; hh[5] = (_Float16)v1.y;
            hh[6] = (_Float16)v1.z; hh[7] = (_Float16)v1.w;
            ah[rt][kc] = hh;
        }
    }

    unsigned m1[8], m2[8], m3[8];          // [rt*4+q] packed keys, descending
    #pragma unroll
    for (int i = 0; i < 8; ++i) { m1[i] = 0u; m2[i] = 0u; m3[i] = 0u; }

    #define STAGE(BUF, CH)                                                                   \
        do {                                                                                 \
            const char* src_ = (const char*)wsE + (size_t)(CH) * 16384 + (size_t)wv * 4096;  \
            char* dst_ = &lds[(BUF)][0] + wv * 4096;                                         \
            _Pragma("unroll")                                                                \
            for (int it = 0; it < 4; ++it) {                                                 \
                __builtin_amdgcn_global_load_lds(                                            \
                    (const __attribute__((address_space(1))) void*)(src_ + it * 1024 + lane * 16), \
                    (__attribute__((address_space(3))) void*)(dst_ + it * 1024),             \
                    16, 0, 0);                                                               \
            }                                                                                \
            if (wv == 0) {                                                                   \
                __builtin_amdgcn_global_load_lds(                                            \
                    (const __attribute__((address_space(1))) void*)(eeW + (size_t)(CH) * 64 + lane), \
                    (__attribute__((address_space(3))) void*)(&lds[(BUF)][0] + 16384),       \
                    4, 0, 0);                                                                \
            }                                                                                \
        } while (0)

    STAGE(0, 0);
    __syncthreads();                       // chunk 0 staged (vmcnt drained by barrier)

    for (int ch = 0; ch < 16; ++ch) {
        if (ch < 15) STAGE((ch + 1) & 1, ch + 1);   // prefetch next chunk
        const char* L = &lds[ch & 1][0];

        #pragma unroll
        for (int ct = 0; ct < 4; ++ct) {
            const int r   = ct * 16 + c;             // code row within chunk (= C col)
            const int swz = (r & 7) << 4;
            const float eec = *reinterpret_cast<const float*>(L + 16384 + (r << 2));
            f32x4 acc0 = {-eec, -eec, -eec, -eec};   // fold -eeW into C-in (one code/column)
            f32x4 acc1 = {-eec, -eec, -eec, -eec};
            #pragma unroll
            for (int kc = 0; kc < 4; ++kc) {
                int bo = (r << 8) + (((kc << 6) + (g << 4)) ^ swz);
                half8 bh = *reinterpret_cast<const half8*>(L + bo);
                acc0 = __builtin_amdgcn_mfma_f32_16x16x32_f16(ah[0][kc], bh, acc0, 0, 0, 0);
                acc1 = __builtin_amdgcn_mfma_f32_16x16x32_f16(ah[1][kc], bh, acc1, 0, 0, 0);
            }
            const unsigned codeC = (unsigned)(1023 - (ch * 64 + r));
            #pragma unroll
            for (int q = 0; q < 4; ++q) {
                #pragma unroll
                for (int rt = 0; rt < 2; ++rt) {
                    float sp = (rt ? acc1[q] : acc0[q]);          // > 0 (bias +512)
                    unsigned u   = __builtin_bit_cast(unsigned, sp);
                    unsigned key = (u & 0xFFFFFC00u) | codeC;     // v_and_or
                    const int i = rt * 4 + q;
                    m3[i] = med3u(m2[i], m3[i], key);             // uses old m2
                    m2[i] = med3u(m1[i], m2[i], key);
                    m1[i] = umax_(m1[i], key);
                }
            }
        }
        __syncthreads();   // prefetched loads drained; buffers safe to swap
    }

    // merge top-3 across the 16 code-lanes of each g-group; stash in LDS
    int* lbest = reinterpret_cast<int*>(&lds[0][0]);
    #pragma unroll
    for (int rt = 0; rt < 2; ++rt) {
        #pragma unroll
        for (int q = 0; q < 4; ++q) {
            const int i = rt * 4 + q;
            unsigned a1 = m1[i], a2 = m2[i], a3 = m3[i];
            #pragma unroll
            for (int mk = 1; mk < 16; mk <<= 1) {
                unsigned b1 = (unsigned)__shfl_xor((int)a1, mk, 64);
                unsigned b2 = (unsigned)__shfl_xor((int)a2, mk, 64);
                unsigned b3 = (unsigned)__shfl_xor((int)a3, mk, 64);
                unsigned c1 = umax_(a1, b1), t1 = (a1 < b1 ? a1 : b1);
                unsigned u1 = umax_(a2, b2), u2 = (a2 < b2 ? a2 : b2);
                unsigned c2 = umax_(t1, u1), t2 = (t1 < u1 ? t1 : u1);
                unsigned c3 = umax_(umax_(t2, u2), umax_(a3, b3));
                a1 = c1; a2 = c2; a3 = c3;
            }
            if (c == 0) {
                int lrow = wv * 32 + rt * 16 + g * 4 + q;
                int i1 = 1023 - (int)(a1 & 1023u);
                int i2 = 1023 - (int)(a2 & 1023u);
                int i3 = 1023 - (int)(a3 & 1023u);
                lbest[lrow] = i1 | (i2 << 10) | (i3 << 20);
            }
        }
    }
    __syncthreads();

    // ---- epilogue: exact fp32 over 3 candidates, gather, loss (2 thr/row) ----
    {
        const int lrow = tid >> 1, hf = tid & 1;
        const int grow = blockbase + lrow;
        const int pk = lbest[lrow];
        const int ia = pk & 1023, ib = (pk >> 10) & 1023, ic = (pk >> 20) & 1023;

        const float4* xv4 = reinterpret_cast<const float4*>(x + (size_t)grow * DIM + hf * 64);
        float4 xr[16];
        #pragma unroll
        for (int i = 0; i < 16; ++i) xr[i] = xv4[i];

        const float4* ea = reinterpret_cast<const float4*>(emb + (size_t)ia * DIM + hf * 64);
        const float4* eb = reinterpret_cast<const float4*>(emb + (size_t)ib * DIM + hf * 64);
        const float4* ec = reinterpret_cast<const float4*>(emb + (size_t)ic * DIM + hf * 64);
        float da = 0.f, db = 0.f, dc = 0.f;
        #pragma unroll
        for (int i = 0; i < 16; ++i) {
            float4 va = ea[i], vb = eb[i], vc = ec[i], xx = xr[i];
            float ax = va.x - xx.x, ay = va.y - xx.y, az = va.z - xx.z, aw = va.w - xx.w;
            float bx = vb.x - xx.x, by = vb.y - xx.y, bz = vb.z - xx.z, bw = vb.w - xx.w;
            float cx = vc.x - xx.x, cy = vc.y - xx.y, cz = vc.z - xx.z, cw = vc.w - xx.w;
            da += ax * ax + ay * ay + az * az + aw * aw;
            db += bx * bx + by * by + bz * bz + bw * bw;
            dc += cx * cx + cy * cy + cz * cz + cw * cw;
        }
        da += __shfl_xor(da, 1, 64);
        db += __shfl_xor(db, 1, 64);
        dc += __shfl_xor(dc, 1, 64);

        int idx = ia; float dm = da;
        if (db < dm || (db == dm && ib < idx)) { dm = db; idx = ib; }
        if (dc < dm || (dc == dm && ic < idx)) { dm = dc; idx = ic; }

        if (hf == 0) out[grow] = (float)idx;

        const float4* q4 = reinterpret_cast<const float4*>(emb + (size_t)idx * DIM + hf * 64);
        float4* oq = reinterpret_cast<float4*>(out + (size_t)NPTS + (size_t)grow * DIM + hf * 64);
        float lsum = 0.f;
        #pragma unroll
        for (int i = 0; i < 16; ++i) {
            float4 qv = q4[i];
            oq[i] = qv;
            float dx = qv.x - xr[i].x;
            float dy = qv.y - xr[i].y;
            float dz = qv.z - xr[i].z;
            float dw = qv.w - xr[i].w;
            lsum += dx * dx + dy * dy + dz * dz + dw * dw;
        }
        __shared__ float red[4];
        #pragma unroll
        for (int o = 32; o > 0; o >>= 1) lsum += __shfl_down(lsum, o);
        if (lane == 0) red[wv] = lsum;
        __syncthreads();
        if (tid == 0) bsum[blockIdx.x] = (red[0] + red[1]) + (red[2] + red[3]);
    }
    #undef STAGE
}

__global__ void vq_finalize(const float* __restrict__ bsum, float* __restrict__ out) {
    __shared__ float red[16];
    int t = threadIdx.x;  // 1024 threads
    float v = bsum[t];
    #pragma unroll
    for (int o = 32; o > 0; o >>= 1) v += __shfl_down(v, o);
    if ((t & 63) == 0) red[t >> 6] = v;
    __syncthreads();
    if (t == 0) {
        float s = 0.f;
        #pragma unroll
        for (int i = 0; i < 16; ++i) s += red[i];
        out[(size_t)NPTS + (size_t)NPTS * DIM] = 1.25f * s / 16777216.0f;
    }
}

// ---- fallback (round-2 proven path; eeW bias is argmax-safe) ----
__global__ void vq_ee(const float* __restrict__ emb, float* __restrict__ eeW) {
    int gid  = blockIdx.x * blockDim.x + threadIdx.x;
    int w    = gid >> 6;
    int lane = threadIdx.x & 63;
    const float* e = emb + (size_t)w * DIM;
    float a = e[lane];
    float b = e[lane + 64];
    float v = a * a + b * b;
    #pragma unroll
    for (int o = 32; o > 0; o >>= 1) v += __shfl_down(v, o);
    if (lane == 0) eeW[w] = 0.5f * v - 512.0f;
}

__global__ __launch_bounds__(256, 1) void vq_main(const float* __restrict__ x,
                                                  const float* __restrict__ emb,
                                                  const float* __restrict__ eeW,
                                                  float* __restrict__ out,
                                                  float* __restrict__ bsum) {
    const int p = blockIdx.x * 256 + threadIdx.x;
    float4 xr[32];
    const float4* xv = reinterpret_cast<const float4*>(x + (size_t)p * DIM);
    #pragma unroll
    for (int i = 0; i < 32; ++i) xr[i] = xv[i];
    float bestv = -3.4e38f; int bi = 0;
    for (int k = 0; k < KC; ++k) {
        const int ku = __builtin_amdgcn_readfirstlane(k);
        const float4* e4 = reinterpret_cast<const float4*>(emb + (size_t)ku * DIM);
        float a0 = 0.f, a1 = 0.f, a2 = 0.f, a3 = 0.f;
        #pragma unroll
        for (int i = 0; i < 32; ++i) {
            float4 ev = e4[i];
            a0 = fmaf(xr[i].x, ev.x, a0);
            a1 = fmaf(xr[i].y, ev.y, a1);
            a2 = fmaf(xr[i].z, ev.z, a2);
            a3 = fmaf(xr[i].w, ev.w, a3);
        }
        float s = ((a0 + a1) + (a2 + a3)) - eeW[ku];
        if (s > bestv) { bestv = s; bi = k; }
    }
    out[p] = (float)bi;
    const float4* q4 = reinterpret_cast<const float4*>(emb + (size_t)bi * DIM);
    float4* oq = reinterpret_cast<float4*>(out + (size_t)NPTS + (size_t)p * DIM);
    float lsum = 0.f;
    #pragma unroll
    for (int i = 0; i < 32; ++i) {
        float4 qv = q4[i];
        oq[i] = qv;
        float dx = qv.x - xr[i].x;
        float dy = qv.y - xr[i].y;
        float dz = qv.z - xr[i].z;
        float dw = qv.w - xr[i].w;
        lsum += dx * dx + dy * dy + dz * dz + dw * dw;
    }
    __shared__ float red[4];
    #pragma unroll
    for (int o = 32; o > 0; o >>= 1) lsum += __shfl_down(lsum, o);
    int lane = threadIdx.x & 63, wvl = threadIdx.x >> 6;
    if (lane == 0) red[wvl] = lsum;
    __syncthreads();
    if (threadIdx.x == 0) bsum[blockIdx.x] = (red[0] + red[1]) + (red[2] + red[3]);
}

__global__ void vq_finalize512(const float* __restrict__ bsum, float* __restrict__ out) {
    __shared__ float red[8];
    int t = threadIdx.x;  // 512 threads
    float v = bsum[t];
    #pragma unroll
    for (int o = 32; o > 0; o >>= 1) v += __shfl_down(v, o);
    if ((t & 63) == 0) red[t >> 6] = v;
    __syncthreads();
    if (t == 0) {
        float s = 0.f;
        #pragma unroll
        for (int i = 0; i < 8; ++i) s += red[i];
        out[(size_t)NPTS + (size_t)NPTS * DIM] = 1.25f * s / 16777216.0f;
    }
}

extern "C" void kernel_launch(void* const* d_in, const int* in_sizes, int n_in,
                              void* d_out, int out_size, void* d_ws, size_t ws_size,
                              hipStream_t stream) {
    const float* x   = (const float*)d_in[0];
    const float* emb = (const float*)d_in[1];
    float* out = (float*)d_out;
    char*  ws  = (char*)d_ws;

    if (ws_size >= 270336) {
        unsigned short* wsE = (unsigned short*)ws;           // 256 KB f16 image
        float* eeW  = (float*)(ws + 262144);                 // 4 KB
        float* bsum = (float*)(ws + 266240);                 // 4 KB
        vq_prep<<<256, 256, 0, stream>>>(emb, wsE, eeW);
        vq_mfma<<<1024, 256, 0, stream>>>(x, emb, wsE, eeW, out, bsum);
        vq_finalize<<<1, 1024, 0, stream>>>(bsum, out);
    } else {
        float* eeW  = (float*)ws;
        float* bsum = (float*)ws + 1024;
        vq_ee<<<256, 256, 0, stream>>>(emb, eeW);
        vq_main<<<512, 256, 0, stream>>>(x, emb, eeW, out, bsum);
        vq_finalize512<<<1, 512, 0, stream>>>(bsum, out);
    }
}

// Round 8
// 107.441 us; speedup vs baseline: 2.2559x; 1.0961x over previous
//
#include <hip/hip_runtime.h>

#define NPTS 131072
#define DIM  128
#define KC   1024
#define CHB  16640   // LDS chunk buffer: 16KB swizzled f16 codes + 256B eeW

using half8 = __attribute__((ext_vector_type(8))) _Float16;
using f32x4 = __attribute__((ext_vector_type(4))) float;

static __device__ __forceinline__ unsigned umax_(unsigned a, unsigned b){ return a > b ? a : b; }
static __device__ __forceinline__ unsigned med3u(unsigned a, unsigned b, unsigned c){
    unsigned d;
    asm("v_med3_u32 %0, %1, %2, %3" : "=v"(d) : "v"(a), "v"(b), "v"(c));
    return d;
}

// ws layout (bytes):
//   [0, 262144)        f16 codebook image, 16 chunks x 16KB, pre-swizzled
//   [262144, 266240)   eeW[1024] = 0.5*||e||^2 - 512   (chunk-contiguous)
//   [266240, 270336)   bsum[1024]

// ---- prep: f16 swizzled image + eeW, one wave per code ----
__global__ void vq_prep(const float* __restrict__ emb, unsigned short* __restrict__ wsE,
                        float* __restrict__ eeW) {
    int lane = threadIdx.x & 63, wv = threadIdx.x >> 6;
    int code = blockIdx.x * 4 + wv;                 // 256 blocks x 4 waves = 1024 codes
    const float* e = emb + (size_t)code * DIM;
    float a = e[lane], b = e[lane + 64];

    int chunk = code >> 6, r = code & 63, swz = (r & 7) << 4;
    size_t base = (size_t)chunk * 16384 + (size_t)(r << 8);
    _Float16 ha = (_Float16)a, hb = (_Float16)b;
    wsE[(base + (size_t)(((lane << 1))        ^ swz)) >> 1] = __builtin_bit_cast(unsigned short, ha);
    wsE[(base + (size_t)(((lane + 64) << 1)   ^ swz)) >> 1] = __builtin_bit_cast(unsigned short, hb);

    float v = a * a + b * b;
    #pragma unroll
    for (int o = 32; o > 0; o >>= 1) v += __shfl_down(v, o);
    if (lane == 0) eeW[code] = 0.5f * v - 512.0f;
}

// ---- fused pass: 16x16x32 f16 MFMA + med3 top-3 + exact-fp32 epilogue ----
__global__ __launch_bounds__(256, 4) void vq_mfma(const float* __restrict__ x,
                                                  const float* __restrict__ emb,
                                                  const unsigned short* __restrict__ wsE,
                                                  const float* __restrict__ eeW,
                                                  float* __restrict__ out,
                                                  float* __restrict__ bsum) {
    __shared__ __attribute__((aligned(128))) char lds[2][CHB];
    const int tid  = threadIdx.x;
    const int lane = tid & 63, wv = tid >> 6;
    const int g    = lane >> 4, c = lane & 15;
    const int blockbase = blockIdx.x * 128;

    // A fragments: x row (blockbase + wv*32 + rt*16 + c), k = kc*32 + g*8 + j
    half8 ah[2][4];
    #pragma unroll
    for (int rt = 0; rt < 2; ++rt) {
        const float* xr = x + (size_t)(blockbase + wv * 32 + rt * 16 + c) * DIM;
        #pragma unroll
        for (int kc = 0; kc < 4; ++kc) {
            const float4* p = reinterpret_cast<const float4*>(xr + kc * 32 + g * 8);
            float4 v0 = p[0], v1 = p[1];
            half8 hh;
            hh[0] = (_Float16)v0.x; hh[1] = (_Float16)v0.y;
            hh[2] = (_Float16)v0.z; hh[3] = (_Float16)v0.w;
            hh[4] = (_Float16)v1.x; hh[5] = (_Float16)v1.y;
            hh[6] = (_Float16)v1.z; hh[7] = (_Float16)v1.w;
            ah[rt][kc] = hh;
        }
    }

    unsigned m1[8], m2[8], m3[8];          // [rt*4+q] packed keys, descending
    #pragma unroll
    for (int i = 0; i < 8; ++i) { m1[i] = 0u; m2[i] = 0u; m3[i] = 0u; }

    #define STAGE(BUF, CH)                                                                   \
        do {                                                                                 \
            const char* src_ = (const char*)wsE + (size_t)(CH) * 16384 + (size_t)wv * 4096;  \
            char* dst_ = &lds[(BUF)][0] + wv * 4096;                                         \
            _Pragma("unroll")                                                                \
            for (int it = 0; it < 4; ++it) {                                                 \
                __builtin_amdgcn_global_load_lds(                                            \
                    (const __attribute__((address_space(1))) void*)(src_ + it * 1024 + lane * 16), \
                    (__attribute__((address_space(3))) void*)(dst_ + it * 1024),             \
                    16, 0, 0);                                                               \
            }                                                                                \
            if (wv == 0) {                                                                   \
                __builtin_amdgcn_global_load_lds(                                            \
                    (const __attribute__((address_space(1))) void*)(eeW + (size_t)(CH) * 64 + lane), \
                    (__attribute__((address_space(3))) void*)(&lds[(BUF)][0] + 16384),       \
                    4, 0, 0);                                                                \
            }                                                                                \
        } while (0)

    // register pipeline: B-frags + eec for the next ct, loaded one ct ahead
    #define PRELOAD(L_, CT_)                                                                 \
        do {                                                                                 \
            const int rp_  = (CT_) * 16 + c;                                                 \
            const int swp_ = (rp_ & 7) << 4;                                                 \
            _Pragma("unroll")                                                                \
            for (int kc = 0; kc < 4; ++kc)                                                   \
                bq[kc] = *reinterpret_cast<const half8*>((L_) + (rp_ << 8) + (((kc << 6) + (g << 4)) ^ swp_)); \
            eecq = *reinterpret_cast<const float*>((L_) + 16384 + (rp_ << 2));               \
        } while (0)

    half8 bq[4]; float eecq;

    STAGE(0, 0);
    __syncthreads();                       // chunk 0 staged (vmcnt drained by barrier)
    PRELOAD(&lds[0][0], 0);

    for (int ch = 0; ch < 16; ++ch) {
        if (ch < 15) STAGE((ch + 1) & 1, ch + 1);   // prefetch next chunk
        const char* L = &lds[ch & 1][0];

        #pragma unroll
        for (int ct = 0; ct < 4; ++ct) {
            half8 b0 = bq[0], b1v = bq[1], b2v = bq[2], b3v = bq[3];
            const float eec = eecq;
            if (ct < 3) PRELOAD(L, ct + 1);          // hide ds_read latency under MFMAs

            f32x4 acc0 = {-eec, -eec, -eec, -eec};   // fold -eeW into C-in (one code/column)
            f32x4 acc1 = {-eec, -eec, -eec, -eec};
            acc0 = __builtin_amdgcn_mfma_f32_16x16x32_f16(ah[0][0], b0,  acc0, 0, 0, 0);
            acc1 = __builtin_amdgcn_mfma_f32_16x16x32_f16(ah[1][0], b0,  acc1, 0, 0, 0);
            acc0 = __builtin_amdgcn_mfma_f32_16x16x32_f16(ah[0][1], b1v, acc0, 0, 0, 0);
            acc1 = __builtin_amdgcn_mfma_f32_16x16x32_f16(ah[1][1], b1v, acc1, 0, 0, 0);
            acc0 = __builtin_amdgcn_mfma_f32_16x16x32_f16(ah[0][2], b2v, acc0, 0, 0, 0);
            acc1 = __builtin_amdgcn_mfma_f32_16x16x32_f16(ah[1][2], b2v, acc1, 0, 0, 0);
            acc0 = __builtin_amdgcn_mfma_f32_16x16x32_f16(ah[0][3], b3v, acc0, 0, 0, 0);
            acc1 = __builtin_amdgcn_mfma_f32_16x16x32_f16(ah[1][3], b3v, acc1, 0, 0, 0);

            const unsigned codeC = (unsigned)(1023 - (ch * 64 + ct * 16 + c));
            #pragma unroll
            for (int q = 0; q < 4; ++q) {
                #pragma unroll
                for (int rt = 0; rt < 2; ++rt) {
                    float sp = (rt ? acc1[q] : acc0[q]);          // > 0 (bias +512)
                    unsigned u   = __builtin_bit_cast(unsigned, sp);
                    unsigned key = (u & 0xFFFFFC00u) | codeC;     // v_and_or
                    const int i = rt * 4 + q;
                    m3[i] = med3u(m2[i], m3[i], key);             // uses old m2
                    m2[i] = med3u(m1[i], m2[i], key);
                    m1[i] = umax_(m1[i], key);
                }
            }
        }
        __syncthreads();   // prefetched loads drained; buffers safe to swap
        if (ch < 15) PRELOAD(&lds[(ch + 1) & 1][0], 0);
    }

    // ---- early-issue half of the exact-x loads (hide HBM under the merge) ----
    const int lrow = tid >> 1, hf = tid & 1;
    const int grow = blockbase + lrow;
    const float4* xv4 = reinterpret_cast<const float4*>(x + (size_t)grow * DIM + hf * 64);
    float4 xr[16];
    #pragma unroll
    for (int i = 0; i < 8; ++i) xr[i] = xv4[i];

    // merge top-3 across the 16 code-lanes of each g-group; stash in LDS
    int* lbest = reinterpret_cast<int*>(&lds[0][0]);
    #pragma unroll
    for (int rt = 0; rt < 2; ++rt) {
        #pragma unroll
        for (int q = 0; q < 4; ++q) {
            const int i = rt * 4 + q;
            unsigned a1 = m1[i], a2 = m2[i], a3 = m3[i];
            #pragma unroll
            for (int mk = 1; mk < 16; mk <<= 1) {
                unsigned b1 = (unsigned)__shfl_xor((int)a1, mk, 64);
                unsigned b2 = (unsigned)__shfl_xor((int)a2, mk, 64);
                unsigned b3 = (unsigned)__shfl_xor((int)a3, mk, 64);
                unsigned c1 = umax_(a1, b1), t1 = (a1 < b1 ? a1 : b1);
                unsigned u1 = umax_(a2, b2), u2 = (a2 < b2 ? a2 : b2);
                unsigned c2 = umax_(t1, u1), t2 = (t1 < u1 ? t1 : u1);
                unsigned c3 = umax_(umax_(t2, u2), umax_(a3, b3));
                a1 = c1; a2 = c2; a3 = c3;
            }
            if (c == 0) {
                int lr = wv * 32 + rt * 16 + g * 4 + q;
                int i1 = 1023 - (int)(a1 & 1023u);
                int i2 = 1023 - (int)(a2 & 1023u);
                int i3 = 1023 - (int)(a3 & 1023u);
                lbest[lr] = i1 | (i2 << 10) | (i3 << 20);
            }
        }
    }
    __syncthreads();

    // remaining exact-x loads
    #pragma unroll
    for (int i = 8; i < 16; ++i) xr[i] = xv4[i];

    // ---- epilogue: exact fp32 over 3 candidates, gather, loss (2 thr/row) ----
    {
        const int pk = lbest[lrow];
        const int ia = pk & 1023, ib = (pk >> 10) & 1023, ic = (pk >> 20) & 1023;

        const float4* ea = reinterpret_cast<const float4*>(emb + (size_t)ia * DIM + hf * 64);
        const float4* eb = reinterpret_cast<const float4*>(emb + (size_t)ib * DIM + hf * 64);
        const float4* ec = reinterpret_cast<const float4*>(emb + (size_t)ic * DIM + hf * 64);
        float da = 0.f, db = 0.f, dc = 0.f;
        #pragma unroll
        for (int i = 0; i < 16; ++i) {
            float4 va = ea[i], vb = eb[i], vc = ec[i], xx = xr[i];
            float ax = va.x - xx.x, ay = va.y - xx.y, az = va.z - xx.z, aw = va.w - xx.w;
            float bx = vb.x - xx.x, by = vb.y - xx.y, bz = vb.z - xx.z, bw = vb.w - xx.w;
            float cx = vc.x - xx.x, cy = vc.y - xx.y, cz = vc.z - xx.z, cw = vc.w - xx.w;
            da += ax * ax + ay * ay + az * az + aw * aw;
            db += bx * bx + by * by + bz * bz + bw * bw;
            dc += cx * cx + cy * cy + cz * cz + cw * cw;
        }
        da += __shfl_xor(da, 1, 64);
        db += __shfl_xor(db, 1, 64);
        dc += __shfl_xor(dc, 1, 64);

        int idx = ia; float dm = da;
        if (db < dm || (db == dm && ib < idx)) { dm = db; idx = ib; }
        if (dc < dm || (dc == dm && ic < idx)) { dm = dc; idx = ic; }

        if (hf == 0) out[grow] = (float)idx;

        const float4* q4 = reinterpret_cast<const float4*>(emb + (size_t)idx * DIM + hf * 64);
        float4* oq = reinterpret_cast<float4*>(out + (size_t)NPTS + (size_t)grow * DIM + hf * 64);
        #pragma unroll
        for (int i = 0; i < 16; ++i) oq[i] = q4[i];

        float lsum = (hf == 0) ? dm : 0.f;   // dm = exact ||x-q||^2 for the chosen code
        __shared__ float red[4];
        #pragma unroll
        for (int o = 32; o > 0; o >>= 1) lsum += __shfl_down(lsum, o);
        if (lane == 0) red[wv] = lsum;
        __syncthreads();
        if (tid == 0) bsum[blockIdx.x] = (red[0] + red[1]) + (red[2] + red[3]);
    }
    #undef STAGE
    #undef PRELOAD
}

__global__ void vq_finalize(const float* __restrict__ bsum, float* __restrict__ out) {
    __shared__ float red[16];
    int t = threadIdx.x;  // 1024 threads
    float v = bsum[t];
    #pragma unroll
    for (int o = 32; o > 0; o >>= 1) v += __shfl_down(v, o);
    if ((t & 63) == 0) red[t >> 6] = v;
    __syncthreads();
    if (t == 0) {
        float s = 0.f;
        #pragma unroll
        for (int i = 0; i < 16; ++i) s += red[i];
        out[(size_t)NPTS + (size_t)NPTS * DIM] = 1.25f * s / 16777216.0f;
    }
}

// ---- fallback (round-2 proven path; eeW bias is argmax-safe) ----
__global__ void vq_ee(const float* __restrict__ emb, float* __restrict__ eeW) {
    int gid  = blockIdx.x * blockDim.x + threadIdx.x;
    int w    = gid >> 6;
    int lane = threadIdx.x & 63;
    const float* e = emb + (size_t)w * DIM;
    float a = e[lane];
    float b = e[lane + 64];
    float v = a * a + b * b;
    #pragma unroll
    for (int o = 32; o > 0; o >>= 1) v += __shfl_down(v, o);
    if (lane == 0) eeW[w] = 0.5f * v - 512.0f;
}

__global__ __launch_bounds__(256, 1) void vq_main(const float* __restrict__ x,
                                                  const float* __restrict__ emb,
                                                  const float* __restrict__ eeW,
                                                  float* __restrict__ out,
                                                  float* __restrict__ bsum) {
    const int p = blockIdx.x * 256 + threadIdx.x;
    float4 xr[32];
    const float4* xv = reinterpret_cast<const float4*>(x + (size_t)p * DIM);
    #pragma unroll
    for (int i = 0; i < 32; ++i) xr[i] = xv[i];
    float bestv = -3.4e38f; int bi = 0;
    for (int k = 0; k < KC; ++k) {
        const int ku = __builtin_amdgcn_readfirstlane(k);
        const float4* e4 = reinterpret_cast<const float4*>(emb + (size_t)ku * DIM);
        float a0 = 0.f, a1 = 0.f, a2 = 0.f, a3 = 0.f;
        #pragma unroll
        for (int i = 0; i < 32; ++i) {
            float4 ev = e4[i];
            a0 = fmaf(xr[i].x, ev.x, a0);
            a1 = fmaf(xr[i].y, ev.y, a1);
            a2 = fmaf(xr[i].z, ev.z, a2);
            a3 = fmaf(xr[i].w, ev.w, a3);
        }
        float s = ((a0 + a1) + (a2 + a3)) - eeW[ku];
        if (s > bestv) { bestv = s; bi = k; }
    }
    out[p] = (float)bi;
    const float4* q4 = reinterpret_cast<const float4*>(emb + (size_t)bi * DIM);
    float4* oq = reinterpret_cast<float4*>(out + (size_t)NPTS + (size_t)p * DIM);
    float lsum = 0.f;
    #pragma unroll
    for (int i = 0; i < 32; ++i) {
        float4 qv = q4[i];
        oq[i] = qv;
        float dx = qv.x - xr[i].x;
        float dy = qv.y - xr[i].y;
        float dz = qv.z - xr[i].z;
        float dw = qv.w - xr[i].w;
        lsum += dx * dx + dy * dy + dz * dz + dw * dw;
    }
    __shared__ float red[4];
    #pragma unroll
    for (int o = 32; o > 0; o >>= 1) lsum += __shfl_down(lsum, o);
    int lane = threadIdx.x & 63, wvl = threadIdx.x >> 6;
    if (lane == 0) red[wvl] = lsum;
    __syncthreads();
    if (threadIdx.x == 0) bsum[blockIdx.x] = (red[0] + red[1]) + (red[2] + red[3]);
}

__global__ void vq_finalize512(const float* __restrict__ bsum, float* __restrict__ out) {
    __shared__ float red[8];
    int t = threadIdx.x;  // 512 threads
    float v = bsum[t];
    #pragma unroll
    for (int o = 32; o > 0; o >>= 1) v += __shfl_down(v, o);
    if ((t & 63) == 0) red[t >> 6] = v;
    __syncthreads();
    if (t == 0) {
        float s = 0.f;
        #pragma unroll
        for (int i = 0; i < 8; ++i) s += red[i];
        out[(size_t)NPTS + (size_t)NPTS * DIM] = 1.25f * s / 16777216.0f;
    }
}

extern "C" void kernel_launch(void* const* d_in, const int* in_sizes, int n_in,
                              void* d_out, int out_size, void* d_ws, size_t ws_size,
                              hipStream_t stream) {
    const float* x   = (const float*)d_in[0];
    const float* emb = (const float*)d_in[1];
    float* out = (float*)d_out;
    char*  ws  = (char*)d_ws;

    if (ws_size >= 270336) {
        unsigned short* wsE = (unsigned short*)ws;           // 256 KB f16 image
        float* eeW  = (float*)(ws + 262144);                 // 4 KB
        float* bsum = (float*)(ws + 266240);                 // 4 KB
        vq_prep<<<256, 256, 0, stream>>>(emb, wsE, eeW);
        vq_mfma<<<1024, 256, 0, stream>>>(x, emb, wsE, eeW, out, bsum);
        vq_finalize<<<1, 1024, 0, stream>>>(bsum, out);
    } else {
        float* eeW  = (float*)ws;
        float* bsum = (float*)ws + 1024;
        vq_ee<<<256, 256, 0, stream>>>(emb, eeW);
        vq_main<<<512, 256, 0, stream>>>(x, emb, eeW, out, bsum);
        vq_finalize512<<<1, 512, 0, stream>>>(bsum, out);
    }
}